// Round 6
// baseline (315.446 us; speedup 1.0000x reference)
//
#include <hip/hip_runtime.h>

typedef _Float16 half8_t __attribute__((ext_vector_type(8)));
typedef _Float16 half4_t __attribute__((ext_vector_type(4)));
typedef float    float4_t __attribute__((ext_vector_type(4)));

#define OMEGA_C 30.0f

// lgkm-only barrier: LDS ops drain, global loads/stores stay in flight (T4).
#define BARRIER() do {                                        \
    asm volatile("s_waitcnt lgkmcnt(0)" ::: "memory");        \
    __builtin_amdgcn_s_barrier();                             \
    asm volatile("" ::: "memory");                            \
  } while (0)

// ---- W staging: [64k][128n] f32 -> LDS [n][k-granule] f16, double-XOR swizzle.
// phys granule = g ^ (n&7) ^ (2*((n>>5)&3)); i-rotation makes writes conflict-free.
#define W_ISSUE(dst, wgp, sW)                                                   \
  do {                                                                          \
    _Pragma("unroll")                                                           \
    for (int j_ = 0; j_ < 4; ++j_)                                              \
      dst[j_] = *(const float4_t*)((wgp) + (size_t)((sW) * 64 + kq * 4 + j_) * 256 + nq * 4); \
  } while (0)

#define W_STORE(src, buf)                                                       \
  do {                                                                          \
    _Pragma("unroll")                                                           \
    for (int ii_ = 0; ii_ < 4; ++ii_) {                                         \
      const int ip_ = (ii_ + nq) & 3;                                           \
      const int n_  = nq * 4 + ip_;                                             \
      half4_t hb_ = {(_Float16)src[0][ip_], (_Float16)src[1][ip_],              \
                     (_Float16)src[2][ip_], (_Float16)src[3][ip_]};             \
      const int pg_ = (kq >> 1) ^ (n_ & 7) ^ (2 * ((n_ >> 5) & 3));             \
      *(half4_t*)&Wl[buf][n_ * 64 + pg_ * 8 + (kq & 1) * 4] = hb_;              \
    }                                                                           \
  } while (0)

// ---- x staging: one instr = one full 1KB row (lane*16B contiguous) ----
#define X_ISSUE(xgp, hb)                                                        \
  do {                                                                          \
    _Pragma("unroll")                                                           \
    for (int j_ = 0; j_ < 4; ++j_)                                              \
      xr[j_] = *(const float4_t*)((xgp) + (size_t)(xrow + (hb) + j_) * 256 + lane * 4); \
  } while (0)

// Xl phys granule = g ^ (row&7) ^ (2*((g>>3)&3)), g = lane>>1 in [0,32)
#define X_COMMIT(hb)                                                            \
  do {                                                                          \
    _Pragma("unroll")                                                           \
    for (int j_ = 0; j_ < 4; ++j_) {                                            \
      const int r_ = xrow + (hb) + j_;                                          \
      half4_t hx_ = {(_Float16)xr[j_].x, (_Float16)xr[j_].y,                    \
                     (_Float16)xr[j_].z, (_Float16)xr[j_].w};                   \
      const int pg_ = (lane >> 1) ^ (r_ & 7) ^ (2 * ((lane >> 4) & 3));         \
      *(half4_t*)&Xl[r_ * 256 + pg_ * 8 + (lane & 1) * 4] = hx_;                \
    }                                                                           \
  } while (0)

// One K-step (64 k) = 2 MFMA halves per acc; all LDS reads conflict-free by swizzle.
#define STEP(sS, buf)                                                           \
  do {                                                                          \
    _Pragma("unroll")                                                           \
    for (int h_ = 0; h_ < 2; ++h_) {                                            \
      half8_t af_[2], bf_[2];                                                   \
      _Pragma("unroll")                                                         \
      for (int m_ = 0; m_ < 2; ++m_) {                                          \
        const int r_ = wm + m_ * 16 + fr;                                       \
        const int u_ = (h_ * 4 + kg) ^ (fr & 7) ^ (2 * ((sS) & 3));             \
        af_[m_] = *(const half8_t*)&Xl[r_ * 256 + ((sS) * 8 + u_) * 8];         \
      }                                                                         \
      _Pragma("unroll")                                                         \
      for (int n_ = 0; n_ < 2; ++n_) {                                          \
        const int r_ = wn + n_ * 16 + fr;                                       \
        const int g_ = (h_ * 4 + kg) ^ (r_ & 7) ^ (2 * ((r_ >> 5) & 3));        \
        bf_[n_] = *(const half8_t*)&Wl[buf][r_ * 64 + g_ * 8];                  \
      }                                                                         \
      _Pragma("unroll")                                                         \
      for (int m_ = 0; m_ < 2; ++m_)                                            \
        _Pragma("unroll")                                                       \
        for (int n_ = 0; n_ < 2; ++n_)                                          \
          acc[m_][n_] = __builtin_amdgcn_mfma_f32_16x16x32_f16(af_[m_], bf_[n_], acc[m_][n_], 0, 0, 0); \
    }                                                                           \
  } while (0)

#define ACC_ZERO()                                                              \
  do {                                                                          \
    _Pragma("unroll")                                                           \
    for (int m_ = 0; m_ < 2; ++m_)                                              \
      _Pragma("unroll")                                                         \
      for (int n_ = 0; n_ < 2; ++n_)                                            \
        acc[m_][n_] = (float4_t){0.f, 0.f, 0.f, 0.f};                           \
  } while (0)

#define EPILOGUE(ogp, nhv)                                                      \
  do {                                                                          \
    _Pragma("unroll")                                                           \
    for (int m_ = 0; m_ < 2; ++m_)                                              \
      _Pragma("unroll")                                                         \
      for (int n_ = 0; n_ < 2; ++n_)                                            \
        _Pragma("unroll")                                                       \
        for (int j_ = 0; j_ < 4; ++j_) {                                        \
          const int row_ = wm + m_ * 16 + kg * 4 + j_;                          \
          const int col_ = wn + n_ * 16 + fr;                                   \
          (ogp)[(size_t)row_ * 256 + col_] =                                    \
              __sinf(fmaf(OMEGA_C, acc[m_][n_][j_], bv[nhv][n_]));              \
        }                                                                       \
  } while (0)

// Persistent: 512 blocks (2/CU), each runs 8 works (tile,mq) = 64x256 output,
// split as nh0/nh1 128-col halves sharing one Xl staging. x is read with full-row
// 1KB contiguous wave-loads; steady state never drains vmcnt to 0.
__global__ __launch_bounds__(512, 4)
void siren_persist(const float* __restrict__ x,
                   const float* __restrict__ wgt,
                   const float* __restrict__ bias,
                   const void* __restrict__ idx_raw,
                   float* __restrict__ out) {
  __shared__ _Float16 Xl[64 * 256];      // 32 KB: [64 rows][256 k] f16, swizzled
  __shared__ _Float16 Wl[2][128 * 64];   // 32 KB: dbuf [128 n][64 k] f16, swizzled

  const int tid  = threadIdx.x;
  const int lane = tid & 63;
  const int wid  = tid >> 6;

  // indices dtype self-detect (int64 per reference; int32 if demoted).
  const int hiw   = ((const int*)idx_raw)[2 * lane + 1];
  const bool is32 = __any(hiw != 0);
  const int* idx32       = (const int*)idx_raw;
  const long long* idx64 = (const long long*)idx_raw;

  const int fr = lane & 15, kg = lane >> 4;
  const int wm = (wid >> 2) * 32;   // wave M origin in 64
  const int wn = (wid & 3) * 32;    // wave N origin in 128
  const int nq = tid & 31, kq = tid >> 5;
  const int xrow = wid * 8;         // x staging rows per wave

  // work units u in [0,4096): tile = u>>2, mq = u&3. 8 consecutive per block, XCD-chunked.
  const int ubase = (blockIdx.x & 7) * 512 + (blockIdx.x >> 3) * 8;

  float bv[2][2];
#pragma unroll
  for (int h = 0; h < 2; ++h)
#pragma unroll
    for (int n = 0; n < 2; ++n)
      bv[h][n] = OMEGA_C * bias[h * 128 + wn + n * 16 + fr];

  int ch_cur;
  { const int t0 = ubase >> 2; ch_cur = is32 ? idx32[t0] : (int)idx64[t0]; }

  float4_t xr[4], wvA[4], wvB[4];

  // ---- pre-loop pipeline fill ----
  {
    const float* Xg0 = x + (size_t)(ubase >> 2) * 65536 + (size_t)(ubase & 3) * 16384;
    X_ISSUE(Xg0, 0);
    X_COMMIT(0);
    X_ISSUE(Xg0, 4);
    const float* Wg0 = wgt + (size_t)ch_cur * 65536;
    W_ISSUE(wvA, Wg0, 0);
  }

#pragma unroll 1
  for (int u = 0; u < 8; ++u) {
    const int uw   = ubase + u;
    const int tile = uw >> 2, mq = uw & 3;
    const float* Wg = wgt + (size_t)ch_cur * 65536;
    float* Og = out + (size_t)tile * 65536 + (size_t)mq * 16384;

    int ch_next = ch_cur;
    if (u < 7) {
      const int tn = (uw + 1) >> 2;
      ch_next = is32 ? idx32[tn] : (int)idx64[tn];
    }

    float4_t acc[2][2];
    ACC_ZERO();

    // top: finish x staging; W s1 issue; W s0 store
    X_COMMIT(4);
    W_ISSUE(wvB, Wg, 1);
    W_STORE(wvA, 0);
    BARRIER();
    // ---- nh0 ----
    STEP(0, 0);  W_ISSUE(wvA, Wg, 2);        W_STORE(wvB, 1);  BARRIER();
    STEP(1, 1);  W_ISSUE(wvB, Wg, 3);        W_STORE(wvA, 0);  BARRIER();
    STEP(2, 0);  W_ISSUE(wvA, Wg + 128, 0);  W_STORE(wvB, 1);  BARRIER();
    STEP(3, 1);  BARRIER();
    // post0: start nh1 staging, drain nh0 epilogue (overlaps)
    W_ISSUE(wvB, Wg + 128, 1);
    W_STORE(wvA, 0);
    EPILOGUE(Og, 0);
    BARRIER();
    ACC_ZERO();
    // ---- nh1 ----
    STEP(0, 0);  W_ISSUE(wvA, Wg + 128, 2);  W_STORE(wvB, 1);  BARRIER();
    STEP(1, 1);  W_ISSUE(wvB, Wg + 128, 3);  W_STORE(wvA, 0);  BARRIER();
    STEP(2, 0);
    if (u < 7) {   // prefetch next work's x, half 1 (contiguous 1KB rows)
      const int un = uw + 1;
      const float* Xgn = x + (size_t)(un >> 2) * 65536 + (size_t)(un & 3) * 16384;
      X_ISSUE(Xgn, 0);
      __builtin_amdgcn_sched_barrier(0);
    }
    W_STORE(wvB, 1);
    BARRIER();
    STEP(3, 1);  BARRIER();
    // post1: commit next x half1 (Xl free now), issue next x half2 + next W s0
    if (u < 7) {
      const int un = uw + 1;
      const float* Xgn = x + (size_t)(un >> 2) * 65536 + (size_t)(un & 3) * 16384;
      X_COMMIT(0);
      X_ISSUE(Xgn, 4);
      const float* Wgn = wgt + (size_t)ch_next * 65536;
      W_ISSUE(wvA, Wgn, 0);
    }
    EPILOGUE(Og + 128, 1);
    ch_cur = ch_next;
  }
}

extern "C" void kernel_launch(void* const* d_in, const int* in_sizes, int n_in,
                              void* d_out, int out_size, void* d_ws, size_t ws_size,
                              hipStream_t stream) {
  const float* x    = (const float*)d_in[0];
  const float* w    = (const float*)d_in[1];
  const float* bias = (const float*)d_in[2];
  const void*  idx  = d_in[3];
  float*       out  = (float*)d_out;

  siren_persist<<<512, 512, 0, stream>>>(x, w, bias, idx, out);
}

// Round 7
// 171.272 us; speedup vs baseline: 1.8418x; 1.8418x over previous
//
#include <hip/hip_runtime.h>

typedef _Float16 half8_t __attribute__((ext_vector_type(8)));
typedef _Float16 half4_t __attribute__((ext_vector_type(4)));
typedef float    float4_t __attribute__((ext_vector_type(4)));

#define OMEGA_C 30.0f
#define LDKA 40   // A row pad: 80 B rows
#define LDKB 36   // B row pad: 72 B rows -> 18-dword stride, conflict-free (gcd(18,32)=2)

// lgkm-only barrier: LDS ops drain, global loads stay in flight across it.
#define BARRIER() do {                                        \
    asm volatile("s_waitcnt lgkmcnt(0)" ::: "memory");        \
    __builtin_amdgcn_s_barrier();                             \
    asm volatile("" ::: "memory");                            \
  } while (0)

// One block = 128x64 output, 256 threads = 4 waves (2M x 2N), acc[4][2] = 32 VGPR.
// Small LDS (29.7 KB) + low VGPR -> 4 independent blocks/CU: phases of different
// blocks interleave so HBM/VALU/MFMA/LDS overlap instead of serializing.
__global__ __launch_bounds__(256, 4)
void siren_tile_gemm(const float* __restrict__ x,
                     const float* __restrict__ w,
                     const float* __restrict__ bias,
                     const void* __restrict__ idx_raw,
                     float* __restrict__ out) {
  __shared__ __align__(16) _Float16 Al[2][128][LDKA];  // 20,480 B
  __shared__ __align__(16) _Float16 Bl[2][64][LDKB];   //  9,216 B

  const int tid = threadIdx.x;

  // XCD-chunked work order: the 8 sub-blocks (2 mh x 4 nq) of a tile are
  // consecutive on one XCD -> x read once from HBM, W shared via L2.
  const int b  = blockIdx.x;             // 0..8191
  const int u  = (b & 7) * 1024 + (b >> 3);
  const int tile = u >> 3;
  const int mh   = (u >> 2) & 1;         // 128-row half
  const int nq   = u & 3;                // 64-col quarter

  // indices dtype self-detect (int64 per reference; int32 if demoted).
  const int hiw   = ((const int*)idx_raw)[2 * (tid & 63) + 1];
  const bool is32 = __any(hiw != 0);
  const int ch = is32 ? ((const int*)idx_raw)[tile]
                      : (int)(((const long long*)idx_raw)[tile]);

  const float* __restrict__ Xg = x + (size_t)tile * 65536 + (size_t)mh * 128 * 256;
  const float* __restrict__ Wg = w + (size_t)ch * 65536 + nq * 64;
  float*       __restrict__ Og = out + (size_t)tile * 65536 + (size_t)mh * 128 * 256 + nq * 64;

  // A staging: 4 passes; pass p: rows 32p + (tid>>3), 8 thr/row, 128 B contiguous per row.
  const int a_row = tid >> 3;            // 0..31 (plus 32p)
  const int a_col = (tid & 7) * 4;       // f32 col within 32-k step
  // B staging: wave w = k-quad; lane n covers one col, rows {4w+j, 16+4w+j}.
  const int b_kq = tid >> 6;             // 0..3
  const int b_n  = tid & 63;             // 0..63

  float4_t acc[4][2];
#pragma unroll
  for (int m = 0; m < 4; ++m)
#pragma unroll
    for (int n = 0; n < 2; ++n)
      acc[m][n] = (float4_t){0.f, 0.f, 0.f, 0.f};

  float4_t xr[4];
  float    wb[8];

#define ISSUE_A(s)                                                              \
  do {                                                                          \
    const int k0_ = (s) * 32;                                                   \
    _Pragma("unroll")                                                           \
    for (int p_ = 0; p_ < 4; ++p_)                                              \
      xr[p_] = *(const float4_t*)(Xg + (size_t)(a_row + 32 * p_) * 256 + k0_ + a_col); \
  } while (0)

#define ISSUE_B(s)                                                              \
  do {                                                                          \
    const int k0_ = (s) * 32;                                                   \
    _Pragma("unroll")                                                           \
    for (int j_ = 0; j_ < 4; ++j_) {                                            \
      wb[j_]     = Wg[(size_t)(k0_ + b_kq * 4 + j_) * 256 + b_n];               \
      wb[j_ + 4] = Wg[(size_t)(k0_ + 16 + b_kq * 4 + j_) * 256 + b_n];          \
    }                                                                           \
  } while (0)

#define STORE_AB(buf)                                                           \
  do {                                                                          \
    _Pragma("unroll")                                                           \
    for (int p_ = 0; p_ < 4; ++p_) {                                            \
      half4_t h_ = {(_Float16)xr[p_].x, (_Float16)xr[p_].y,                     \
                    (_Float16)xr[p_].z, (_Float16)xr[p_].w};                    \
      *(half4_t*)&Al[buf][a_row + 32 * p_][a_col] = h_;                         \
    }                                                                           \
    half4_t hb0_ = {(_Float16)wb[0], (_Float16)wb[1],                           \
                    (_Float16)wb[2], (_Float16)wb[3]};                          \
    half4_t hb1_ = {(_Float16)wb[4], (_Float16)wb[5],                           \
                    (_Float16)wb[6], (_Float16)wb[7]};                          \
    *(half4_t*)&Bl[buf][b_n][b_kq * 4]      = hb0_;                             \
    *(half4_t*)&Bl[buf][b_n][16 + b_kq * 4] = hb1_;                             \
  } while (0)

  // ---- prologue ----
  ISSUE_A(0);
  ISSUE_B(0);
  STORE_AB(0);
  BARRIER();

  const int lane = tid & 63;
  const int wid  = tid >> 6;
  const int wm   = (wid >> 1) * 64;   // wave M origin (0/64)
  const int wn   = (wid & 1) * 32;    // wave N origin (0/32)
  const int fr   = lane & 15;
  const int kg   = lane >> 4;

#pragma unroll 2
  for (int s = 0; s < 8; ++s) {
    const int cur = s & 1;
    if (s + 1 < 8) { ISSUE_A(s + 1); ISSUE_B(s + 1); }

    half8_t af[4], bf[2];
#pragma unroll
    for (int m = 0; m < 4; ++m)
      af[m] = *(const half8_t*)&Al[cur][wm + m * 16 + fr][kg * 8];
#pragma unroll
    for (int n = 0; n < 2; ++n) {
      const int r = wn + n * 16 + fr;
      half4_t lo = *(const half4_t*)&Bl[cur][r][kg * 8];
      half4_t hi = *(const half4_t*)&Bl[cur][r][kg * 8 + 4];
      bf[n] = (half8_t){lo.x, lo.y, lo.z, lo.w, hi.x, hi.y, hi.z, hi.w};
    }

#pragma unroll
    for (int m = 0; m < 4; ++m)
#pragma unroll
      for (int n = 0; n < 2; ++n)
        acc[m][n] = __builtin_amdgcn_mfma_f32_16x16x32_f16(af[m], bf[n], acc[m][n], 0, 0, 0);

    if (s + 1 < 8) {
      STORE_AB(cur ^ 1);
      BARRIER();
    }
  }

  // ---- epilogue: bias + sin (C/D: col=lane&15, row=(lane>>4)*4+j) ----
  float bv[2];
#pragma unroll
  for (int n = 0; n < 2; ++n) bv[n] = OMEGA_C * bias[nq * 64 + wn + n * 16 + fr];

#pragma unroll
  for (int m = 0; m < 4; ++m) {
#pragma unroll
    for (int n = 0; n < 2; ++n) {
#pragma unroll
      for (int j = 0; j < 4; ++j) {
        const int row = wm + m * 16 + kg * 4 + j;
        const int col = wn + n * 16 + fr;
        Og[(size_t)row * 256 + col] = __sinf(fmaf(OMEGA_C, acc[m][n][j], bv[n]));
      }
    }
  }
}

extern "C" void kernel_launch(void* const* d_in, const int* in_sizes, int n_in,
                              void* d_out, int out_size, void* d_ws, size_t ws_size,
                              hipStream_t stream) {
  const float* x    = (const float*)d_in[0];
  const float* w    = (const float*)d_in[1];
  const float* bias = (const float*)d_in[2];
  const void*  idx  = d_in[3];
  float*       out  = (float*)d_out;

  siren_tile_gemm<<<8192, 256, 0, stream>>>(x, w, bias, idx, out);
}